// Round 6
// baseline (912.174 us; speedup 1.0000x reference)
//
#include <hip/hip_runtime.h>
#include <stdint.h>

// ---------------- problem constants ----------------
constexpr int N_GRAPH = 100000;
constexpr int N_CANDS = 10;
constexpr int NT      = N_GRAPH + N_CANDS;   // 100010
constexpr int F_IN    = 128;
constexpr int NTYPES  = 10;
constexpr int NE      = 6400000;

constexpr int CB_SHIFT = 8;                   // 256 nodes per coarse bucket (R6: was 512)
constexpr int CB       = 1 << CB_SHIFT;
constexpr int NBK2     = (NT + CB - 1) / CB;  // 391 buckets -> k_place grid covers all 256 CUs
constexpr int SB       = 512;                 // scatter blocks (also bcount blocks)
constexpr int NMAT     = NBK2 * SB;           // 200192 (scan matrix size)
constexpr int NSCAN_B  = NMAT / 512;          // 391 scan blocks (512-thread scan blocks)
constexpr int TMPENT_CAP = NE + NMAT * 7 + 8; // regions padded to 8 slots (32B) -> 31.2MB, no ws growth

#define RNG_VARIANT 0

typedef float f4v __attribute__((ext_vector_type(4)));

// ---------------- threefry2x32 (matches jax._src.prng) ----------------
__device__ __forceinline__ void tf2x32(uint32_t k0, uint32_t k1, uint32_t x0, uint32_t x1,
                                       uint32_t& o0, uint32_t& o1) {
  const uint32_t ks2 = k0 ^ k1 ^ 0x1BD11BDAu;
  uint32_t v0 = x0 + k0, v1 = x1 + k1;
#define TFR(r) { v0 += v1; v1 = (v1 << (r)) | (v1 >> (32 - (r))); v1 ^= v0; }
  TFR(13) TFR(15) TFR(26) TFR(6)
  v0 += k1;  v1 += ks2 + 1u;
  TFR(17) TFR(29) TFR(16) TFR(24)
  v0 += ks2; v1 += k0 + 2u;
  TFR(13) TFR(15) TFR(26) TFR(6)
  v0 += k0;  v1 += k1 + 3u;
  TFR(17) TFR(29) TFR(16) TFR(24)
  v0 += k1;  v1 += ks2 + 4u;
  TFR(13) TFR(15) TFR(26) TFR(6)
  v0 += ks2; v1 += k0 + 5u;
#undef TFR
  o0 = v0; o1 = v1;
}

__device__ __forceinline__ void derive_keys(uint32_t& a0, uint32_t& a1,
                                            uint32_t& b0, uint32_t& b1) {
#if RNG_VARIANT == 2
  uint32_t c0, c1, d0, d1;
  tf2x32(0u, 42u, 0u, 2u, c0, c1);
  tf2x32(0u, 42u, 1u, 3u, d0, d1);
  a0 = c0; a1 = d0; b0 = c1; b1 = d1;
#else
  tf2x32(0u, 42u, 0u, 0u, a0, a1);
  tf2x32(0u, 42u, 0u, 1u, b0, b1);
#endif
}

__device__ __forceinline__ uint32_t rng_bits(uint32_t k0, uint32_t k1,
                                             uint32_t idx, uint32_t total) {
#if RNG_VARIANT == 0
  uint32_t o0, o1; tf2x32(k0, k1, 0u, idx, o0, o1); return o0 ^ o1;
#elif RNG_VARIANT == 1
  uint32_t o0, o1; tf2x32(k0, k1, 0u, idx, o0, o1); return o1;
#else
  uint32_t half = total >> 1; uint32_t o0, o1;
  if (idx < half) { tf2x32(k0, k1, idx, idx + half, o0, o1); return o0; }
  tf2x32(k0, k1, idx - half, idx, o0, o1); return o1;
#endif
}

__device__ __forceinline__ double gumbel_from_bits(uint32_t bits) {
  float uf = __uint_as_float((bits >> 9) | 0x3f800000u) - 1.0f;  // [0,1)
  uf = fmaxf(1.17549435e-38f, uf + 1.17549435e-38f);
  return -log(-log((double)uf));
}

__device__ __forceinline__ uint32_t encf(float f) {
  uint32_t u = __float_as_uint(f);
  return u ^ ((u & 0x80000000u) ? 0xFFFFFFFFu : 0x80000000u);
}
__device__ __forceinline__ float decf(uint32_t e) {
  uint32_t u = (e & 0x80000000u) ? (e ^ 0x80000000u) : ~e;
  return __uint_as_float(u);
}

// ---------------- CSR build ----------------
__global__ __launch_bounds__(512) void k_bcount(const int* __restrict__ dst,
                                                int* __restrict__ cntmat,
                                                int* __restrict__ cnt) {
  __shared__ int h[NBK2];
  int tid = threadIdx.x, blk = blockIdx.x;
  for (int b = tid; b < NBK2; b += 512) h[b] = 0;
  __syncthreads();
  int per = (NE + SB - 1) / SB;
  int e0 = blk * per, e1 = min(e0 + per, NE);
  for (int e = e0 + tid; e < e1; e += 512) atomicAdd(&h[dst[e] >> CB_SHIFT], 1);
  __syncthreads();
  for (int b = tid; b < NBK2; b += 512) {
    int c = h[b];
    cntmat[b * SB + blk] = (c + 7) & ~7;       // 8-slot (32B) aligned region
    if (c) atomicAdd(&cnt[b], c);
  }
}

__global__ __launch_bounds__(512) void k_s1(int* __restrict__ cmat, int* __restrict__ partial) {
  __shared__ int sm[512];
  int t = blockIdx.x * 512 + threadIdx.x;
  int v = cmat[t];
  sm[threadIdx.x] = v;
  __syncthreads();
  #pragma unroll
  for (int s = 1; s < 512; s <<= 1) {
    int a = (threadIdx.x >= s) ? sm[threadIdx.x - s] : 0;
    __syncthreads();
    sm[threadIdx.x] += a;
    __syncthreads();
  }
  cmat[t] = sm[threadIdx.x] - v;               // block-local exclusive
  if (threadIdx.x == 511) partial[blockIdx.x] = sm[511];
}

// s2: scans the per-block partials AND (merged) the per-bucket counts -> rowbase
__global__ __launch_bounds__(512) void k_s2(int* __restrict__ partial, int* __restrict__ cmat,
                                            const int* __restrict__ cnt, int* __restrict__ rowbase) {
  __shared__ int sm[512];
  int t = threadIdx.x;
  int v = (t < NSCAN_B) ? partial[t] : 0;
  sm[t] = v;
  __syncthreads();
  #pragma unroll
  for (int s = 1; s < 512; s <<= 1) {
    int a = (t >= s) ? sm[t - s] : 0;
    __syncthreads();
    sm[t] += a;
    __syncthreads();
  }
  if (t < NSCAN_B) partial[t] = sm[t] - v;     // exclusive
  if (t == 511) cmat[NMAT] = sm[511];          // grand total
  __syncthreads();
  // merged rowscan: exclusive scan of cnt[NBK2] -> rowbase
  int v2 = (t < NBK2) ? cnt[t] : 0;
  sm[t] = v2;
  __syncthreads();
  #pragma unroll
  for (int s = 1; s < 512; s <<= 1) {
    int a = (t >= s) ? sm[t - s] : 0;
    __syncthreads();
    sm[t] += a;
    __syncthreads();
  }
  if (t < NBK2) rowbase[t] = sm[t] - v2;
}

__global__ __launch_bounds__(512) void k_s3(int* __restrict__ cmat, const int* __restrict__ partial) {
  int t = blockIdx.x * 512 + threadIdx.x;
  cmat[t] += partial[blockIdx.x];
}

__global__ __launch_bounds__(512) void k_scatter2(const int* __restrict__ src,
                                                  const int* __restrict__ dst,
                                                  const int* __restrict__ cmat,
                                                  uint32_t* __restrict__ tmpent) {
  __shared__ int lcur[NBK2];
  int tid = threadIdx.x, blk = blockIdx.x;
  for (int b = tid; b < NBK2; b += 512) lcur[b] = cmat[b * SB + blk];
  __syncthreads();
  int per = (NE + SB - 1) / SB;
  int e0 = blk * per, e1 = min(e0 + per, NE);
  for (int e = e0 + tid; e < e1; e += 512) {
    int s = src[e], d = dst[e];
    int b = d >> CB_SHIFT;
    int pos = atomicAdd(&lcur[b], 1);
    tmpent[pos] = (uint32_t)s | ((uint32_t)(d & (CB - 1)) << 17);
  }
  __syncthreads();
  for (int b = tid; b < NBK2; b += 512) {
    int p = lcur[b];
    int end = cmat[b * SB + blk + 1];
    for (; p < end; ++p) tmpent[p] = 0xFFFFFFFFu;
  }
}

// 391 blocks x 256 threads (R6): full CU coverage + multiple resident blocks/CU
// (old 196x512 grid left 60 CUs idle -> 78.7us @ 14.9% occupancy)
__global__ __launch_bounds__(256) void k_place(const uint32_t* __restrict__ tmpent,
                                               const int* __restrict__ cmat,
                                               const int* __restrict__ rowbase,
                                               int* __restrict__ rowptr,
                                               float* __restrict__ dinv,
                                               int* __restrict__ col) {
  __shared__ int sdeg[CB];
  __shared__ int sexc[CB];
  __shared__ int sscan[CB];
  int b = blockIdx.x, tid = threadIdx.x;
  sdeg[tid] = 0;
  __syncthreads();
  int r0 = cmat[b * SB], r1 = cmat[(b + 1) * SB];
  for (int e = r0 + tid; e < r1; e += 256) {
    uint32_t v = tmpent[e];
    if (v != 0xFFFFFFFFu) atomicAdd(&sdeg[v >> 17], 1);
  }
  __syncthreads();
  int d = sdeg[tid];
  sscan[tid] = d;
  __syncthreads();
  #pragma unroll
  for (int s = 1; s < CB; s <<= 1) {
    int v = (tid >= s) ? sscan[tid - s] : 0;
    __syncthreads();
    sscan[tid] += v;
    __syncthreads();
  }
  int rb = rowbase[b];
  int incl = rb + sscan[tid];
  sexc[tid] = incl - d;
  int i = b * CB + tid;
  if (i < NT) {
    rowptr[i + 1] = incl;
    dinv[i] = (float)(1.0 / sqrt((double)(d + 1)));
  }
  if (b == 0 && tid == 0) rowptr[0] = 0;
  __syncthreads();
  for (int e = r0 + tid; e < r1; e += 256) {
    uint32_t v = tmpent[e];
    if (v != 0xFFFFFFFFu) {
      int pos = atomicAdd(&sexc[v >> 17], 1);
      col[pos] = (int)(v & 0x1FFFFu);
    }
  }
}

// ---------------- zs0 = (concat(x,cand) @ W1) * dinv   [NT,16], 4 features/thread ----------------
__global__ __launch_bounds__(256) void k_mm1(const float* __restrict__ x, const float* __restrict__ cand,
                                             const float* __restrict__ W, const float* __restrict__ dinv,
                                             float* __restrict__ zs0) {
  int gid = blockIdx.x * 256 + threadIdx.x;
  if (gid >= NT * 4) return;
  int i = gid >> 2, f4 = gid & 3;
  const float* hr = (i < N_GRAPH) ? (x + (size_t)i * F_IN)
                                  : (cand + (size_t)(i - N_GRAPH) * F_IN);
  const float4* h4 = reinterpret_cast<const float4*>(hr);
  const float4* W4 = reinterpret_cast<const float4*>(W);   // W[k][16] -> W4[k*4 + f4]
  double a0 = 0.0, a1 = 0.0, a2 = 0.0, a3 = 0.0;
  #pragma unroll 8
  for (int q = 0; q < 32; ++q) {
    float4 hv = h4[q];
    float4 w0 = W4[(4 * q + 0) * 4 + f4];
    float4 w1 = W4[(4 * q + 1) * 4 + f4];
    float4 w2 = W4[(4 * q + 2) * 4 + f4];
    float4 w3 = W4[(4 * q + 3) * 4 + f4];
    a0 += (double)hv.x * w0.x + (double)hv.y * w1.x + (double)hv.z * w2.x + (double)hv.w * w3.x;
    a1 += (double)hv.x * w0.y + (double)hv.y * w1.y + (double)hv.z * w2.y + (double)hv.w * w3.y;
    a2 += (double)hv.x * w0.z + (double)hv.y * w1.z + (double)hv.z * w2.z + (double)hv.w * w3.z;
    a3 += (double)hv.x * w0.w + (double)hv.y * w1.w + (double)hv.z * w2.w + (double)hv.w * w3.w;
  }
  double di = (double)dinv[i];
  float4 o;
  o.x = (float)(a0 * di); o.y = (float)(a1 * di);
  o.z = (float)(a2 * di); o.w = (float)(a3 * di);
  reinterpret_cast<float4*>(zs0)[(size_t)i * 4 + f4] = o;
}

// ---------------- 16-feature propagation, 1 cacheline per edge-gather, edge-split ----------------
// Wall (R0-R5): ~8.5-10 cyc per distinct 64B line-touch per CU, invariant to L2/L3
// service tier and to bytes (R1: 2x lines at equal bytes = 2x time; R5: L2-resident
// split = no gain). So: single pass, 64B rows, minimum line count (6.4M/prop).
// Per row: 8 threads = fx{0..3} x es{0,1}; es lanes alternate 4-edge groups
// (partner = lane^4); x2 unroll keeps 8 gathers in flight per lane, order-preserving.
template <bool SQ, bool WITHW, int R>
__global__ __launch_bounds__(8 * R) void k_prop3(const int* __restrict__ rowptr,
                                                 const int* __restrict__ col,
                                                 const float* __restrict__ zin,   // [NT][16]
                                                 const float* __restrict__ win,   // [NT] scaled w input
                                                 const float* __restrict__ dinv,
                                                 float* __restrict__ zout,        // [NT][16]
                                                 float* __restrict__ wout,        // unscaled w_{l}
                                                 float* __restrict__ wsout) {     // dinv*w (next prop input)
  int i = blockIdx.x * R + threadIdx.y;
  if (i >= NT) return;
  int fx = threadIdx.x & 3;          // 16B feature quad -> 64B row = 1 line
  int es = threadIdx.x >> 2;         // edge-split lane (0/1); wave partner = lane^4
  const float4* z4 = reinterpret_cast<const float4*>(zin);
  int e0 = rowptr[i], e1 = rowptr[i + 1];
  int ngrp = (e1 - e0) >> 2;         // full 4-edge groups
  double a0 = 0.0, a1 = 0.0, a2 = 0.0, a3 = 0.0, wa = 0.0;
  const bool dow = WITHW && (fx == 0);
  int gq = es;
  // x2 unroll: groups gq and gq+2 issued together (8 gathers in flight), adds in
  // the same order as the sequential loop
  for (; gq + 4 <= ngrp; gq += 4) {
    int ea = e0 + (gq << 2);
    int eb = e0 + ((gq + 2) << 2);
    int c0 = __builtin_nontemporal_load(col + ea);
    int c1 = __builtin_nontemporal_load(col + ea + 1);
    int c2 = __builtin_nontemporal_load(col + ea + 2);
    int c3 = __builtin_nontemporal_load(col + ea + 3);
    int c4 = __builtin_nontemporal_load(col + eb);
    int c5 = __builtin_nontemporal_load(col + eb + 1);
    int c6 = __builtin_nontemporal_load(col + eb + 2);
    int c7 = __builtin_nontemporal_load(col + eb + 3);
    float4 v0 = z4[(size_t)c0 * 4 + fx];
    float4 v1 = z4[(size_t)c1 * 4 + fx];
    float4 v2 = z4[(size_t)c2 * 4 + fx];
    float4 v3 = z4[(size_t)c3 * 4 + fx];
    float4 v4 = z4[(size_t)c4 * 4 + fx];
    float4 v5 = z4[(size_t)c5 * 4 + fx];
    float4 v6 = z4[(size_t)c6 * 4 + fx];
    float4 v7 = z4[(size_t)c7 * 4 + fx];
    if (dow) {
      wa += (double)win[c0] + (double)win[c1] + (double)win[c2] + (double)win[c3];
      wa += (double)win[c4] + (double)win[c5] + (double)win[c6] + (double)win[c7];
    }
    a0 += (double)v0.x + (double)v1.x + (double)v2.x + (double)v3.x;
    a1 += (double)v0.y + (double)v1.y + (double)v2.y + (double)v3.y;
    a2 += (double)v0.z + (double)v1.z + (double)v2.z + (double)v3.z;
    a3 += (double)v0.w + (double)v1.w + (double)v2.w + (double)v3.w;
    a0 += (double)v4.x + (double)v5.x + (double)v6.x + (double)v7.x;
    a1 += (double)v4.y + (double)v5.y + (double)v6.y + (double)v7.y;
    a2 += (double)v4.z + (double)v5.z + (double)v6.z + (double)v7.z;
    a3 += (double)v4.w + (double)v5.w + (double)v6.w + (double)v7.w;
  }
  for (; gq < ngrp; gq += 2) {
    int e = e0 + (gq << 2);
    int c0 = __builtin_nontemporal_load(col + e);
    int c1 = __builtin_nontemporal_load(col + e + 1);
    int c2 = __builtin_nontemporal_load(col + e + 2);
    int c3 = __builtin_nontemporal_load(col + e + 3);
    float4 v0 = z4[(size_t)c0 * 4 + fx];
    float4 v1 = z4[(size_t)c1 * 4 + fx];
    float4 v2 = z4[(size_t)c2 * 4 + fx];
    float4 v3 = z4[(size_t)c3 * 4 + fx];
    if (dow)
      wa += (double)win[c0] + (double)win[c1] + (double)win[c2] + (double)win[c3];
    a0 += (double)v0.x + (double)v1.x + (double)v2.x + (double)v3.x;
    a1 += (double)v0.y + (double)v1.y + (double)v2.y + (double)v3.y;
    a2 += (double)v0.z + (double)v1.z + (double)v2.z + (double)v3.z;
    a3 += (double)v0.w + (double)v1.w + (double)v2.w + (double)v3.w;
  }
  // tail (<4 edges) handled by the es lane that keeps group parity
  if (es == (ngrp & 1)) {
    for (int e = e0 + (ngrp << 2); e < e1; ++e) {
      int c = __builtin_nontemporal_load(col + e);
      float4 v = z4[(size_t)c * 4 + fx];
      if (dow) wa += (double)win[c];
      a0 += (double)v.x; a1 += (double)v.y; a2 += (double)v.z; a3 += (double)v.w;
    }
  }
  // combine es partners (lane ^ 4); both lanes of a row exit together at i>=NT
  a0 += __shfl_xor(a0, 4);
  a1 += __shfl_xor(a1, 4);
  a2 += __shfl_xor(a2, 4);
  a3 += __shfl_xor(a3, 4);
  if (WITHW) wa += __shfl_xor(wa, 4);
  if (es == 0) {
    float4 s = z4[(size_t)i * 4 + fx];
    a0 += (double)s.x; a1 += (double)s.y; a2 += (double)s.z; a3 += (double)s.w;
    double di = (double)dinv[i];
    double sc = SQ ? di * di : di;
    float4 o;
    o.x = (float)(sc * a0); o.y = (float)(sc * a1);
    o.z = (float)(sc * a2); o.w = (float)(sc * a3);
    reinterpret_cast<float4*>(zout)[(size_t)i * 4 + fx] = o;
    if (dow) {
      wa += (double)win[i];
      double w = di * wa;                 // unscaled w_{l}
      wout[i]  = (float)w;
      wsout[i] = (float)(di * w);         // scaled for next prop
    }
  }
}

// ---------------- small dense precompute: M = W2@W3, u = b1@W2@W3, v = b2@W3 ----------------
__global__ __launch_bounds__(512) void k_small(const float* __restrict__ W2, const float* __restrict__ b2p,
                                               const float* __restrict__ W3, const float* __restrict__ b1p,
                                               double* __restrict__ M, double* __restrict__ u,
                                               double* __restrict__ v) {
  __shared__ double t[24];
  int tid = threadIdx.x;
  if (tid < 24) {
    double a = 0.0;
    for (int k = 0; k < 16; ++k) a += (double)b1p[k] * (double)W2[k * 24 + tid];
    t[tid] = a;
  }
  if (tid >= 32 && tid < 64) {
    int o = tid - 32;
    double a = 0.0;
    for (int j = 0; j < 24; ++j) a += (double)b2p[j] * (double)W3[j * 32 + o];
    v[o] = a;
  }
  __syncthreads();
  if (tid < 32) {
    double a = 0.0;
    for (int j = 0; j < 24; ++j) a += t[j] * (double)W3[j * 32 + tid];
    u[tid] = a;
  }
  {
    int k = tid >> 5, o = tid & 31;
    double a = 0.0;
    for (int j = 0; j < 24; ++j) a += (double)W2[k * 24 + j] * (double)W3[j * 32 + o];
    M[tid] = a;
  }
}

// ---------------- epilogue: h3 = z3@M + w2 (x) u + w1 (x) v + b3 ----------------
__global__ __launch_bounds__(256) void k_epi(const float* __restrict__ z3, const float* __restrict__ w1,
                                             const float* __restrict__ w2,
                                             const double* __restrict__ M, const double* __restrict__ u,
                                             const double* __restrict__ v, const float* __restrict__ b3,
                                             float* __restrict__ H) {
  int gid = blockIdx.x * 256 + threadIdx.x;
  if (gid >= NT * 32) return;
  int i = gid >> 5, o = gid & 31;
  const float* zr = z3 + (size_t)i * 16;
  double acc = (double)b3[o] + (double)w2[i] * u[o] + (double)w1[i] * v[o];
  #pragma unroll
  for (int k = 0; k < 16; ++k) acc += (double)zr[k] * M[k * 32 + o];
  H[gid] = (float)acc;
}

// ---------------- heads / softmax / sampling ----------------
template <int HID>
__global__ __launch_bounds__(256) void k_head(const float* __restrict__ H, const int* __restrict__ sn,
                                              int nrows,
                                              const float* __restrict__ Wa, const float* __restrict__ ba,
                                              const float* __restrict__ Wb, const float* __restrict__ bb,
                                              float* __restrict__ logits) {
  int i = blockIdx.x * 256 + threadIdx.x;
  if (i >= nrows) return;
  int row = (i < NT) ? i : sn[i - NT];
  const float* hr = H + (size_t)row * 32;
  float h[32];
  #pragma unroll
  for (int k = 0; k < 32; ++k) h[k] = hr[k];
  double hid[HID];
  for (int j = 0; j < HID; ++j) {
    double a = (double)ba[j];
    #pragma unroll
    for (int k = 0; k < 32; ++k) a += (double)h[k] * (double)Wa[k * HID + j];
    hid[j] = fmin(fmax(a, 0.0), 6.0);  // relu6
  }
  for (int t = 0; t < NTYPES; ++t) {
    double l = (double)bb[t];
    #pragma unroll
    for (int j = 0; j < HID; ++j) l += hid[j] * (double)Wb[j * NTYPES + t];
    logits[(size_t)i * NTYPES + t] = (float)l;
  }
}

__global__ __launch_bounds__(256) void k_colmax(const float* __restrict__ L, int nrows,
                                                uint32_t* __restrict__ mb) {
  __shared__ float sm[256][NTYPES];
  float m[NTYPES];
  #pragma unroll
  for (int t = 0; t < NTYPES; ++t) m[t] = -3.402823466e38f;
  for (int r = blockIdx.x * 256 + threadIdx.x; r < nrows; r += gridDim.x * 256) {
    #pragma unroll
    for (int t = 0; t < NTYPES; ++t) m[t] = fmaxf(m[t], L[(size_t)r * NTYPES + t]);
  }
  #pragma unroll
  for (int t = 0; t < NTYPES; ++t) sm[threadIdx.x][t] = m[t];
  __syncthreads();
  for (int s = 128; s > 0; s >>= 1) {
    if (threadIdx.x < s)
      for (int t = 0; t < NTYPES; ++t)
        sm[threadIdx.x][t] = fmaxf(sm[threadIdx.x][t], sm[threadIdx.x + s][t]);
    __syncthreads();
  }
  if (threadIdx.x < NTYPES) atomicMax(&mb[threadIdx.x], encf(sm[0][threadIdx.x]));
}

__global__ __launch_bounds__(256) void k_colsum(const float* __restrict__ L, int nrows,
                                                const uint32_t* __restrict__ mb,
                                                double* __restrict__ sums) {
  __shared__ double sm[256][NTYPES];
  float mx[NTYPES];
  #pragma unroll
  for (int t = 0; t < NTYPES; ++t) mx[t] = decf(mb[t]);
  double s[NTYPES];
  #pragma unroll
  for (int t = 0; t < NTYPES; ++t) s[t] = 0.0;
  for (int r = blockIdx.x * 256 + threadIdx.x; r < nrows; r += gridDim.x * 256) {
    #pragma unroll
    for (int t = 0; t < NTYPES; ++t)
      s[t] += exp((double)L[(size_t)r * NTYPES + t] - (double)mx[t]);
  }
  #pragma unroll
  for (int t = 0; t < NTYPES; ++t) sm[threadIdx.x][t] = s[t];
  __syncthreads();
  for (int st = 128; st > 0; st >>= 1) {
    if (threadIdx.x < st)
      for (int t = 0; t < NTYPES; ++t)
        sm[threadIdx.x][t] += sm[threadIdx.x + st][t];
    __syncthreads();
  }
  if (threadIdx.x < NTYPES) atomicAdd(&sums[threadIdx.x], sm[0][threadIdx.x]);
}

// ---------------- fused probs + gumbel sampling (start head) ----------------
__global__ __launch_bounds__(256) void k_ps_start(const float* __restrict__ L,
                                                  const uint32_t* __restrict__ mb,
                                                  const double* __restrict__ sums,
                                                  float* __restrict__ P,
                                                  float* __restrict__ outSN,
                                                  int* __restrict__ sn,
                                                  int* __restrict__ flags) {
  int i = blockIdx.x * 256 + threadIdx.x;
  if (i >= NT) return;
  uint32_t a0, a1, b0, b1; derive_keys(a0, a1, b0, b1);
  double best = -1e300; int bi = 0;
  #pragma unroll
  for (int t = 0; t < NTYPES; ++t) {
    double p = exp((double)L[(size_t)i * NTYPES + t] - (double)decf(mb[t])) / sums[t];
    float pf = (float)p;
    if (i >= N_GRAPH || pf == 0.0f) pf = 1e-10f;
    P[(size_t)i * NTYPES + t] = pf;
    uint32_t bits = rng_bits(a0, a1, (uint32_t)(i * NTYPES + t), (uint32_t)(NT * NTYPES));
    double v = log((double)pf) + gumbel_from_bits(bits);
    if (v > best) { best = v; bi = t; }
  }
  sn[i] = bi;
  outSN[i] = (float)bi;
  flags[bi] = 1;   // benign race: all writers store 1
}

// ---------------- fused probs + gumbel sampling (end head) ----------------
__global__ __launch_bounds__(256) void k_ps_end(const float* __restrict__ L,
                                                const uint32_t* __restrict__ mb,
                                                const double* __restrict__ sums,
                                                const int* __restrict__ flags,
                                                float* __restrict__ P,
                                                float* __restrict__ outEN) {
  int j = blockIdx.x * 256 + threadIdx.x;
  if (j >= 2 * NT) return;
  uint32_t a0, a1, b0, b1; derive_keys(a0, a1, b0, b1);
  const bool rowmask = (j < NTYPES && flags[j]);
  double best = -1e300; int bi = 0;
  #pragma unroll
  for (int t = 0; t < NTYPES; ++t) {
    double p = exp((double)L[(size_t)j * NTYPES + t] - (double)decf(mb[t])) / sums[t];
    float pf = (float)p;
    if (rowmask || pf == 0.0f) pf = 1e-10f;
    P[(size_t)j * NTYPES + t] = pf;
    uint32_t bits = rng_bits(b0, b1, (uint32_t)(j * NTYPES + t), (uint32_t)(2 * NT * NTYPES));
    double v = log((double)pf) + gumbel_from_bits(bits);
    if (v > best) { best = v; bi = t; }
  }
  outEN[j] = (float)bi;
}

// ---------------- host ----------------
extern "C" void kernel_launch(void* const* d_in, const int* in_sizes, int n_in,
                              void* d_out, int out_size, void* d_ws, size_t ws_size,
                              hipStream_t stream) {
  const float* x    = (const float*)d_in[0];
  const float* cand = (const float*)d_in[1];
  const int*   ei   = (const int*)d_in[2];
  const float* W1 = (const float*)d_in[4];  const float* b1 = (const float*)d_in[5];
  const float* W2 = (const float*)d_in[6];  const float* b2 = (const float*)d_in[7];
  const float* W3 = (const float*)d_in[8];  const float* b3 = (const float*)d_in[9];
  const float* Ws1 = (const float*)d_in[10]; const float* bs1 = (const float*)d_in[11];
  const float* Ws2 = (const float*)d_in[12]; const float* bs2 = (const float*)d_in[13];
  const float* We1 = (const float*)d_in[14]; const float* be1 = (const float*)d_in[15];
  const float* We2 = (const float*)d_in[16]; const float* be2 = (const float*)d_in[17];
  float* out = (float*)d_out;
  float* outSN = out;
  float* outEN = out + NT;
  float* outPS = out + 3 * NT;
  float* outPE = out + 13 * NT;

  char* ws = (char*)d_ws;
  size_t off = 0;
  auto alloc = [&](size_t bytes) -> void* {
    void* p = ws + off;
    off += (bytes + 511) & ~(size_t)511;
    return p;
  };
  float*    dinv    = (float*)alloc((size_t)NT * 4);
  int*      rowptr  = (int*)alloc((size_t)(NT + 1) * 4);
  int*      cnt     = (int*)alloc((size_t)NBK2 * 4);
  int*      rowbase = (int*)alloc((size_t)NBK2 * 4);
  int*      cmat    = (int*)alloc((size_t)(NMAT + 1) * 4);
  int*      partial = (int*)alloc(512 * 4);
  int*      col     = (int*)alloc((size_t)NE * 4);
  // tmpent (~31.2 MB) aliases zsA + zsB + Ha (all dead until after k_place)
  char*     ublk    = (char*)alloc((size_t)TMPENT_CAP * 4);
  uint32_t* tmpent  = (uint32_t*)ublk;
  float*    zsA     = (float*)ublk;                                    // [NT][16] = 6.4 MB
  float*    zsB     = (float*)(ublk + (size_t)NT * 16 * 4);            // [NT][16] = 6.4 MB
  float*    Ha      = (float*)(ublk + (size_t)NT * 16 * 4 * 2);        // 12.8 MB
  float*    logitsS = (float*)alloc((size_t)NT * NTYPES * 4);
  float*    logitsE = (float*)alloc((size_t)2 * NT * NTYPES * 4);
  float*    w1v     = (float*)alloc((size_t)NT * 4);
  float*    ws1v    = (float*)alloc((size_t)NT * 4);
  float*    w2v     = (float*)alloc((size_t)NT * 4);
  float*    wsd     = (float*)alloc((size_t)NT * 4);   // dummy scaled-out of prop2
  double*   Md      = (double*)alloc(512 * 8);
  double*   ud      = (double*)alloc(32 * 8);
  double*   vd      = (double*)alloc(32 * 8);
  int*      sn      = (int*)alloc((size_t)NT * 4);
  uint32_t* maxS    = (uint32_t*)alloc(64);
  double*   sumS    = (double*)alloc(128);
  uint32_t* maxE    = (uint32_t*)alloc(64);
  double*   sumE    = (double*)alloc(128);
  int*      flags   = (int*)alloc(64);
  (void)ws_size; (void)in_sizes; (void)n_in; (void)out_size;

  const int* srcA = ei;
  const int* dstA = ei + NE;

  const int B = 256;
  auto blocks = [](long long nthreads) { return (int)((nthreads + 255) / 256); };

  // CSR build: count -> scan (+rowscan merged into s2) -> barrier-free scatter -> place
  hipMemsetAsync(cnt, 0, (size_t)NBK2 * 4, stream);
  k_bcount<<<SB, 512, 0, stream>>>(dstA, cmat, cnt);
  k_s1<<<NSCAN_B, 512, 0, stream>>>(cmat, partial);
  k_s2<<<1, 512, 0, stream>>>(partial, cmat, cnt, rowbase);
  k_s3<<<NSCAN_B, 512, 0, stream>>>(cmat, partial);
  k_scatter2<<<SB, 512, 0, stream>>>(srcA, dstA, cmat, tmpent);
  k_place<<<NBK2, 256, 0, stream>>>(tmpent, cmat, rowbase, rowptr, dinv, col);

  // linear GCN stack folded to three 16-feature propagations (1 cacheline/edge)
  // + scalar w-props + dense epilogue
  k_small<<<1, 512, 0, stream>>>(W2, b2, W3, b1, Md, ud, vd);
  k_mm1<<<blocks((long long)NT * 4), B, 0, stream>>>(x, cand, W1, dinv, zsA);
  const int PR3 = 32, PBLK = (NT + PR3 - 1) / PR3;    // 3126 blocks, 8x32 = 256 thr
  k_prop3<true,  true,  PR3><<<PBLK, dim3(8, PR3), 0, stream>>>(rowptr, col, zsA, dinv, dinv, zsB, w1v, ws1v);
  k_prop3<true,  true,  PR3><<<PBLK, dim3(8, PR3), 0, stream>>>(rowptr, col, zsB, ws1v, dinv, zsA, w2v, wsd);
  k_prop3<false, false, PR3><<<PBLK, dim3(8, PR3), 0, stream>>>(rowptr, col, zsA, nullptr, dinv, zsB, nullptr, nullptr);
  k_epi<<<blocks((long long)NT * 32), B, 0, stream>>>(zsB, w1v, w2v, Md, ud, vd, b3, Ha);
  // H3 = Ha

  // start head
  k_head<16><<<blocks(NT), B, 0, stream>>>(Ha, sn, NT, Ws1, bs1, Ws2, bs2, logitsS);
  hipMemsetAsync(maxS, 0, (size_t)((char*)flags - (char*)maxS) + 512, stream);
  k_colmax<<<512, B, 0, stream>>>(logitsS, NT, maxS);
  k_colsum<<<512, B, 0, stream>>>(logitsS, NT, maxS, sumS);
  k_ps_start<<<blocks(NT), B, 0, stream>>>(logitsS, maxS, sumS, outPS, outSN, sn, flags);

  // end head (rows: [H3; H3[sn]])
  k_head<24><<<blocks(2 * NT), B, 0, stream>>>(Ha, sn, 2 * NT, We1, be1, We2, be2, logitsE);
  k_colmax<<<512, B, 0, stream>>>(logitsE, 2 * NT, maxE);
  k_colsum<<<512, B, 0, stream>>>(logitsE, 2 * NT, maxE, sumE);
  k_ps_end<<<blocks((long long)2 * NT), B, 0, stream>>>(logitsE, maxE, sumE, flags, outPE, outEN);
}

// Round 8
// 775.299 us; speedup vs baseline: 1.1765x; 1.1765x over previous
//
#include <hip/hip_runtime.h>
#include <stdint.h>

// ---------------- problem constants ----------------
constexpr int N_GRAPH = 100000;
constexpr int N_CANDS = 10;
constexpr int NT      = N_GRAPH + N_CANDS;   // 100010
constexpr int F_IN    = 128;
constexpr int NTYPES  = 10;
constexpr int NE      = 6400000;

constexpr int CB_SHIFT = 9;                   // 512 nodes per coarse bucket (R3 champion config)
constexpr int CB       = 1 << CB_SHIFT;
constexpr int NBK2     = (NT + CB - 1) / CB;  // 196
constexpr int SB       = 512;                 // scatter blocks (also bcount blocks)
constexpr int NMAT     = NBK2 * SB;           // 100352 (scan matrix size)
constexpr int NSCAN_B  = NMAT / 256;          // 392 scan blocks
constexpr int TMPENT_CAP = NE + NMAT * 15 + 16;  // all regions padded to 16 slots

#define RNG_VARIANT 0

typedef float f4v __attribute__((ext_vector_type(4)));

// ---------------- threefry2x32 (matches jax._src.prng) ----------------
__device__ __forceinline__ void tf2x32(uint32_t k0, uint32_t k1, uint32_t x0, uint32_t x1,
                                       uint32_t& o0, uint32_t& o1) {
  const uint32_t ks2 = k0 ^ k1 ^ 0x1BD11BDAu;
  uint32_t v0 = x0 + k0, v1 = x1 + k1;
#define TFR(r) { v0 += v1; v1 = (v1 << (r)) | (v1 >> (32 - (r))); v1 ^= v0; }
  TFR(13) TFR(15) TFR(26) TFR(6)
  v0 += k1;  v1 += ks2 + 1u;
  TFR(17) TFR(29) TFR(16) TFR(24)
  v0 += ks2; v1 += k0 + 2u;
  TFR(13) TFR(15) TFR(26) TFR(6)
  v0 += k0;  v1 += k1 + 3u;
  TFR(17) TFR(29) TFR(16) TFR(24)
  v0 += k1;  v1 += ks2 + 4u;
  TFR(13) TFR(15) TFR(26) TFR(6)
  v0 += ks2; v1 += k0 + 5u;
#undef TFR
  o0 = v0; o1 = v1;
}

__device__ __forceinline__ void derive_keys(uint32_t& a0, uint32_t& a1,
                                            uint32_t& b0, uint32_t& b1) {
#if RNG_VARIANT == 2
  uint32_t c0, c1, d0, d1;
  tf2x32(0u, 42u, 0u, 2u, c0, c1);
  tf2x32(0u, 42u, 1u, 3u, d0, d1);
  a0 = c0; a1 = d0; b0 = c1; b1 = d1;
#else
  tf2x32(0u, 42u, 0u, 0u, a0, a1);
  tf2x32(0u, 42u, 0u, 1u, b0, b1);
#endif
}

__device__ __forceinline__ uint32_t rng_bits(uint32_t k0, uint32_t k1,
                                             uint32_t idx, uint32_t total) {
#if RNG_VARIANT == 0
  uint32_t o0, o1; tf2x32(k0, k1, 0u, idx, o0, o1); return o0 ^ o1;
#elif RNG_VARIANT == 1
  uint32_t o0, o1; tf2x32(k0, k1, 0u, idx, o0, o1); return o1;
#else
  uint32_t half = total >> 1; uint32_t o0, o1;
  if (idx < half) { tf2x32(k0, k1, idx, idx + half, o0, o1); return o0; }
  tf2x32(k0, k1, idx - half, idx, o0, o1); return o1;
#endif
}

__device__ __forceinline__ double gumbel_from_bits(uint32_t bits) {
  float uf = __uint_as_float((bits >> 9) | 0x3f800000u) - 1.0f;  // [0,1)
  uf = fmaxf(1.17549435e-38f, uf + 1.17549435e-38f);
  return -log(-log((double)uf));
}

__device__ __forceinline__ uint32_t encf(float f) {
  uint32_t u = __float_as_uint(f);
  return u ^ ((u & 0x80000000u) ? 0xFFFFFFFFu : 0x80000000u);
}
__device__ __forceinline__ float decf(uint32_t e) {
  uint32_t u = (e & 0x80000000u) ? (e ^ 0x80000000u) : ~e;
  return __uint_as_float(u);
}

// ---------------- CSR build ----------------
__global__ __launch_bounds__(512) void k_bcount(const int* __restrict__ dst,
                                                int* __restrict__ cntmat,
                                                int* __restrict__ cnt) {
  __shared__ int h[NBK2];
  int tid = threadIdx.x, blk = blockIdx.x;
  for (int b = tid; b < NBK2; b += 512) h[b] = 0;
  __syncthreads();
  int per = (NE + SB - 1) / SB;
  int e0 = blk * per, e1 = min(e0 + per, NE);
  for (int e = e0 + tid; e < e1; e += 512) atomicAdd(&h[dst[e] >> CB_SHIFT], 1);
  __syncthreads();
  for (int b = tid; b < NBK2; b += 512) {
    int c = h[b];
    cntmat[b * SB + blk] = (c + 15) & ~15;     // 16-slot (64B) aligned region
    if (c) atomicAdd(&cnt[b], c);
  }
}

__global__ __launch_bounds__(256) void k_s1(int* __restrict__ cmat, int* __restrict__ partial) {
  __shared__ int sm[256];
  int t = blockIdx.x * 256 + threadIdx.x;
  int v = cmat[t];
  sm[threadIdx.x] = v;
  __syncthreads();
  #pragma unroll
  for (int s = 1; s < 256; s <<= 1) {
    int a = (threadIdx.x >= s) ? sm[threadIdx.x - s] : 0;
    __syncthreads();
    sm[threadIdx.x] += a;
    __syncthreads();
  }
  cmat[t] = sm[threadIdx.x] - v;               // block-local exclusive
  if (threadIdx.x == 255) partial[blockIdx.x] = sm[255];
}

// s2: scans the per-block partials AND (merged) the per-bucket counts -> rowbase
__global__ __launch_bounds__(512) void k_s2(int* __restrict__ partial, int* __restrict__ cmat,
                                            const int* __restrict__ cnt, int* __restrict__ rowbase) {
  __shared__ int sm[512];
  int t = threadIdx.x;
  int v = (t < NSCAN_B) ? partial[t] : 0;
  sm[t] = v;
  __syncthreads();
  #pragma unroll
  for (int s = 1; s < 512; s <<= 1) {
    int a = (t >= s) ? sm[t - s] : 0;
    __syncthreads();
    sm[t] += a;
    __syncthreads();
  }
  if (t < NSCAN_B) partial[t] = sm[t] - v;     // exclusive
  if (t == 511) cmat[NMAT] = sm[511];          // grand total
  __syncthreads();
  // merged rowscan: exclusive scan of cnt[NBK2] -> rowbase
  int v2 = (t < NBK2) ? cnt[t] : 0;
  sm[t] = v2;
  __syncthreads();
  #pragma unroll
  for (int s = 1; s < 512; s <<= 1) {
    int a = (t >= s) ? sm[t - s] : 0;
    __syncthreads();
    sm[t] += a;
    __syncthreads();
  }
  if (t < NBK2) rowbase[t] = sm[t] - v2;
}

__global__ __launch_bounds__(256) void k_s3(int* __restrict__ cmat, const int* __restrict__ partial) {
  int t = blockIdx.x * 256 + threadIdx.x;
  cmat[t] += partial[blockIdx.x];
}

__global__ __launch_bounds__(512) void k_scatter2(const int* __restrict__ src,
                                                  const int* __restrict__ dst,
                                                  const int* __restrict__ cmat,
                                                  uint32_t* __restrict__ tmpent) {
  __shared__ int lcur[NBK2];
  int tid = threadIdx.x, blk = blockIdx.x;
  for (int b = tid; b < NBK2; b += 512) lcur[b] = cmat[b * SB + blk];
  __syncthreads();
  int per = (NE + SB - 1) / SB;
  int e0 = blk * per, e1 = min(e0 + per, NE);
  for (int e = e0 + tid; e < e1; e += 512) {
    int s = src[e], d = dst[e];
    int b = d >> CB_SHIFT;
    int pos = atomicAdd(&lcur[b], 1);
    tmpent[pos] = (uint32_t)s | ((uint32_t)(d & (CB - 1)) << 17);
  }
  __syncthreads();
  for (int b = tid; b < NBK2; b += 512) {
    int p = lcur[b];
    int end = cmat[b * SB + blk + 1];
    for (; p < end; ++p) tmpent[p] = 0xFFFFFFFFu;
  }
}

__global__ __launch_bounds__(512) void k_place(const uint32_t* __restrict__ tmpent,
                                               const int* __restrict__ cmat,
                                               const int* __restrict__ rowbase,
                                               int* __restrict__ rowptr,
                                               float* __restrict__ dinv,
                                               int* __restrict__ col) {
  __shared__ int sdeg[CB];
  __shared__ int sexc[CB];
  __shared__ int sscan[CB];
  int b = blockIdx.x, tid = threadIdx.x;
  sdeg[tid] = 0;
  __syncthreads();
  int r0 = cmat[b * SB], r1 = cmat[(b + 1) * SB];
  for (int e = r0 + tid; e < r1; e += 512) {
    uint32_t v = tmpent[e];
    if (v != 0xFFFFFFFFu) atomicAdd(&sdeg[v >> 17], 1);
  }
  __syncthreads();
  int d = sdeg[tid];
  sscan[tid] = d;
  __syncthreads();
  #pragma unroll
  for (int s = 1; s < CB; s <<= 1) {
    int v = (tid >= s) ? sscan[tid - s] : 0;
    __syncthreads();
    sscan[tid] += v;
    __syncthreads();
  }
  int rb = rowbase[b];
  int incl = rb + sscan[tid];
  sexc[tid] = incl - d;
  int i = b * CB + tid;
  if (i < NT) {
    rowptr[i + 1] = incl;
    dinv[i] = (float)(1.0 / sqrt((double)(d + 1)));
  }
  if (b == 0 && tid == 0) rowptr[0] = 0;
  __syncthreads();
  for (int e = r0 + tid; e < r1; e += 512) {
    uint32_t v = tmpent[e];
    if (v != 0xFFFFFFFFu) {
      int pos = atomicAdd(&sexc[v >> 17], 1);
      col[pos] = (int)(v & 0x1FFFFu);
    }
  }
}

// ---------------- zs0 = (concat(x,cand) @ W1) * dinv   [NT,16], 4 features/thread ----------------
__global__ __launch_bounds__(256) void k_mm1(const float* __restrict__ x, const float* __restrict__ cand,
                                             const float* __restrict__ W, const float* __restrict__ dinv,
                                             float* __restrict__ zs0) {
  int gid = blockIdx.x * 256 + threadIdx.x;
  if (gid >= NT * 4) return;
  int i = gid >> 2, f4 = gid & 3;
  const float* hr = (i < N_GRAPH) ? (x + (size_t)i * F_IN)
                                  : (cand + (size_t)(i - N_GRAPH) * F_IN);
  const float4* h4 = reinterpret_cast<const float4*>(hr);
  const float4* W4 = reinterpret_cast<const float4*>(W);   // W[k][16] -> W4[k*4 + f4]
  double a0 = 0.0, a1 = 0.0, a2 = 0.0, a3 = 0.0;
  #pragma unroll 8
  for (int q = 0; q < 32; ++q) {
    float4 hv = h4[q];
    float4 w0 = W4[(4 * q + 0) * 4 + f4];
    float4 w1 = W4[(4 * q + 1) * 4 + f4];
    float4 w2 = W4[(4 * q + 2) * 4 + f4];
    float4 w3 = W4[(4 * q + 3) * 4 + f4];
    a0 += (double)hv.x * w0.x + (double)hv.y * w1.x + (double)hv.z * w2.x + (double)hv.w * w3.x;
    a1 += (double)hv.x * w0.y + (double)hv.y * w1.y + (double)hv.z * w2.y + (double)hv.w * w3.y;
    a2 += (double)hv.x * w0.z + (double)hv.y * w1.z + (double)hv.z * w2.z + (double)hv.w * w3.z;
    a3 += (double)hv.x * w0.w + (double)hv.y * w1.w + (double)hv.z * w2.w + (double)hv.w * w3.w;
  }
  double di = (double)dinv[i];
  float4 o;
  o.x = (float)(a0 * di); o.y = (float)(a1 * di);
  o.z = (float)(a2 * di); o.w = (float)(a3 * di);
  reinterpret_cast<float4*>(zs0)[(size_t)i * 4 + f4] = o;
}

// ---------------- 16-feature propagation, 1 cacheline per edge-gather, edge-split ----------------
// Wall (R0-R6): ~9 cyc per distinct 64B line-touch per CU, invariant to L2/L3
// service tier, occupancy, and residency engineering (R2 L2-hit split, R5 col-half
// split: no net gain). Single pass, 64B rows, minimum line count (6.4M/prop).
// Per row: 8 threads = fx{0..3} x es{0,1}; es lanes alternate 4-edge groups
// (partner = lane^4); x2 unroll keeps 8 gathers in flight per lane, order-preserving.
template <bool SQ, bool WITHW, int R>
__global__ __launch_bounds__(8 * R) void k_prop3(const int* __restrict__ rowptr,
                                                 const int* __restrict__ col,
                                                 const float* __restrict__ zin,   // [NT][16]
                                                 const float* __restrict__ win,   // [NT] scaled w input
                                                 const float* __restrict__ dinv,
                                                 float* __restrict__ zout,        // [NT][16]
                                                 float* __restrict__ wout,        // unscaled w_{l}
                                                 float* __restrict__ wsout) {     // dinv*w (next prop input)
  int i = blockIdx.x * R + threadIdx.y;
  if (i >= NT) return;
  int fx = threadIdx.x & 3;          // 16B feature quad -> 64B row = 1 line
  int es = threadIdx.x >> 2;         // edge-split lane (0/1); wave partner = lane^4
  const float4* z4 = reinterpret_cast<const float4*>(zin);
  int e0 = rowptr[i], e1 = rowptr[i + 1];
  int ngrp = (e1 - e0) >> 2;         // full 4-edge groups
  double a0 = 0.0, a1 = 0.0, a2 = 0.0, a3 = 0.0, wa = 0.0;
  const bool dow = WITHW && (fx == 0);
  int gq = es;
  // x2 unroll: groups gq and gq+2 issued together (8 gathers in flight), adds in
  // the same order as the sequential loop
  for (; gq + 4 <= ngrp; gq += 4) {
    int ea = e0 + (gq << 2);
    int eb = e0 + ((gq + 2) << 2);
    int c0 = __builtin_nontemporal_load(col + ea);
    int c1 = __builtin_nontemporal_load(col + ea + 1);
    int c2 = __builtin_nontemporal_load(col + ea + 2);
    int c3 = __builtin_nontemporal_load(col + ea + 3);
    int c4 = __builtin_nontemporal_load(col + eb);
    int c5 = __builtin_nontemporal_load(col + eb + 1);
    int c6 = __builtin_nontemporal_load(col + eb + 2);
    int c7 = __builtin_nontemporal_load(col + eb + 3);
    float4 v0 = z4[(size_t)c0 * 4 + fx];
    float4 v1 = z4[(size_t)c1 * 4 + fx];
    float4 v2 = z4[(size_t)c2 * 4 + fx];
    float4 v3 = z4[(size_t)c3 * 4 + fx];
    float4 v4 = z4[(size_t)c4 * 4 + fx];
    float4 v5 = z4[(size_t)c5 * 4 + fx];
    float4 v6 = z4[(size_t)c6 * 4 + fx];
    float4 v7 = z4[(size_t)c7 * 4 + fx];
    if (dow) {
      wa += (double)win[c0] + (double)win[c1] + (double)win[c2] + (double)win[c3];
      wa += (double)win[c4] + (double)win[c5] + (double)win[c6] + (double)win[c7];
    }
    a0 += (double)v0.x + (double)v1.x + (double)v2.x + (double)v3.x;
    a1 += (double)v0.y + (double)v1.y + (double)v2.y + (double)v3.y;
    a2 += (double)v0.z + (double)v1.z + (double)v2.z + (double)v3.z;
    a3 += (double)v0.w + (double)v1.w + (double)v2.w + (double)v3.w;
    a0 += (double)v4.x + (double)v5.x + (double)v6.x + (double)v7.x;
    a1 += (double)v4.y + (double)v5.y + (double)v6.y + (double)v7.y;
    a2 += (double)v4.z + (double)v5.z + (double)v6.z + (double)v7.z;
    a3 += (double)v4.w + (double)v5.w + (double)v6.w + (double)v7.w;
  }
  for (; gq < ngrp; gq += 2) {
    int e = e0 + (gq << 2);
    int c0 = __builtin_nontemporal_load(col + e);
    int c1 = __builtin_nontemporal_load(col + e + 1);
    int c2 = __builtin_nontemporal_load(col + e + 2);
    int c3 = __builtin_nontemporal_load(col + e + 3);
    float4 v0 = z4[(size_t)c0 * 4 + fx];
    float4 v1 = z4[(size_t)c1 * 4 + fx];
    float4 v2 = z4[(size_t)c2 * 4 + fx];
    float4 v3 = z4[(size_t)c3 * 4 + fx];
    if (dow)
      wa += (double)win[c0] + (double)win[c1] + (double)win[c2] + (double)win[c3];
    a0 += (double)v0.x + (double)v1.x + (double)v2.x + (double)v3.x;
    a1 += (double)v0.y + (double)v1.y + (double)v2.y + (double)v3.y;
    a2 += (double)v0.z + (double)v1.z + (double)v2.z + (double)v3.z;
    a3 += (double)v0.w + (double)v1.w + (double)v2.w + (double)v3.w;
  }
  // tail (<4 edges) handled by the es lane that keeps group parity
  if (es == (ngrp & 1)) {
    for (int e = e0 + (ngrp << 2); e < e1; ++e) {
      int c = __builtin_nontemporal_load(col + e);
      float4 v = z4[(size_t)c * 4 + fx];
      if (dow) wa += (double)win[c];
      a0 += (double)v.x; a1 += (double)v.y; a2 += (double)v.z; a3 += (double)v.w;
    }
  }
  // combine es partners (lane ^ 4); both lanes of a row exit together at i>=NT
  a0 += __shfl_xor(a0, 4);
  a1 += __shfl_xor(a1, 4);
  a2 += __shfl_xor(a2, 4);
  a3 += __shfl_xor(a3, 4);
  if (WITHW) wa += __shfl_xor(wa, 4);
  if (es == 0) {
    float4 s = z4[(size_t)i * 4 + fx];
    a0 += (double)s.x; a1 += (double)s.y; a2 += (double)s.z; a3 += (double)s.w;
    double di = (double)dinv[i];
    double sc = SQ ? di * di : di;
    float4 o;
    o.x = (float)(sc * a0); o.y = (float)(sc * a1);
    o.z = (float)(sc * a2); o.w = (float)(sc * a3);
    reinterpret_cast<float4*>(zout)[(size_t)i * 4 + fx] = o;
    if (dow) {
      wa += (double)win[i];
      double w = di * wa;                 // unscaled w_{l}
      wout[i]  = (float)w;
      wsout[i] = (float)(di * w);         // scaled for next prop
    }
  }
}

// ---------------- small dense precompute: M = W2@W3, u = b1@W2@W3, v = b2@W3 ----------------
__global__ __launch_bounds__(512) void k_small(const float* __restrict__ W2, const float* __restrict__ b2p,
                                               const float* __restrict__ W3, const float* __restrict__ b1p,
                                               double* __restrict__ M, double* __restrict__ u,
                                               double* __restrict__ v) {
  __shared__ double t[24];
  int tid = threadIdx.x;
  if (tid < 24) {
    double a = 0.0;
    for (int k = 0; k < 16; ++k) a += (double)b1p[k] * (double)W2[k * 24 + tid];
    t[tid] = a;
  }
  if (tid >= 32 && tid < 64) {
    int o = tid - 32;
    double a = 0.0;
    for (int j = 0; j < 24; ++j) a += (double)b2p[j] * (double)W3[j * 32 + o];
    v[o] = a;
  }
  __syncthreads();
  if (tid < 32) {
    double a = 0.0;
    for (int j = 0; j < 24; ++j) a += t[j] * (double)W3[j * 32 + tid];
    u[tid] = a;
  }
  {
    int k = tid >> 5, o = tid & 31;
    double a = 0.0;
    for (int j = 0; j < 24; ++j) a += (double)W2[k * 24 + j] * (double)W3[j * 32 + o];
    M[tid] = a;
  }
}

// ---------------- epilogue: h3 = z3@M + w2 (x) u + w1 (x) v + b3 ----------------
__global__ __launch_bounds__(256) void k_epi(const float* __restrict__ z3, const float* __restrict__ w1,
                                             const float* __restrict__ w2,
                                             const double* __restrict__ M, const double* __restrict__ u,
                                             const double* __restrict__ v, const float* __restrict__ b3,
                                             float* __restrict__ H) {
  int gid = blockIdx.x * 256 + threadIdx.x;
  if (gid >= NT * 32) return;
  int i = gid >> 5, o = gid & 31;
  const float* zr = z3 + (size_t)i * 16;
  double acc = (double)b3[o] + (double)w2[i] * u[o] + (double)w1[i] * v[o];
  #pragma unroll
  for (int k = 0; k < 16; ++k) acc += (double)zr[k] * M[k * 32 + o];
  H[gid] = (float)acc;
}

// ---------------- heads / softmax / sampling ----------------
template <int HID>
__global__ __launch_bounds__(256) void k_head(const float* __restrict__ H, const int* __restrict__ sn,
                                              int nrows,
                                              const float* __restrict__ Wa, const float* __restrict__ ba,
                                              const float* __restrict__ Wb, const float* __restrict__ bb,
                                              float* __restrict__ logits) {
  int i = blockIdx.x * 256 + threadIdx.x;
  if (i >= nrows) return;
  int row = (i < NT) ? i : sn[i - NT];
  const float* hr = H + (size_t)row * 32;
  float h[32];
  #pragma unroll
  for (int k = 0; k < 32; ++k) h[k] = hr[k];
  double hid[HID];
  for (int j = 0; j < HID; ++j) {
    double a = (double)ba[j];
    #pragma unroll
    for (int k = 0; k < 32; ++k) a += (double)h[k] * (double)Wa[k * HID + j];
    hid[j] = fmin(fmax(a, 0.0), 6.0);  // relu6
  }
  for (int t = 0; t < NTYPES; ++t) {
    double l = (double)bb[t];
    #pragma unroll
    for (int j = 0; j < HID; ++j) l += hid[j] * (double)Wb[j * NTYPES + t];
    logits[(size_t)i * NTYPES + t] = (float)l;
  }
}

__global__ __launch_bounds__(256) void k_colmax(const float* __restrict__ L, int nrows,
                                                uint32_t* __restrict__ mb) {
  __shared__ float sm[256][NTYPES];
  float m[NTYPES];
  #pragma unroll
  for (int t = 0; t < NTYPES; ++t) m[t] = -3.402823466e38f;
  for (int r = blockIdx.x * 256 + threadIdx.x; r < nrows; r += gridDim.x * 256) {
    #pragma unroll
    for (int t = 0; t < NTYPES; ++t) m[t] = fmaxf(m[t], L[(size_t)r * NTYPES + t]);
  }
  #pragma unroll
  for (int t = 0; t < NTYPES; ++t) sm[threadIdx.x][t] = m[t];
  __syncthreads();
  for (int s = 128; s > 0; s >>= 1) {
    if (threadIdx.x < s)
      for (int t = 0; t < NTYPES; ++t)
        sm[threadIdx.x][t] = fmaxf(sm[threadIdx.x][t], sm[threadIdx.x + s][t]);
    __syncthreads();
  }
  if (threadIdx.x < NTYPES) atomicMax(&mb[threadIdx.x], encf(sm[0][threadIdx.x]));
}

__global__ __launch_bounds__(256) void k_colsum(const float* __restrict__ L, int nrows,
                                                const uint32_t* __restrict__ mb,
                                                double* __restrict__ sums) {
  __shared__ double sm[256][NTYPES];
  float mx[NTYPES];
  #pragma unroll
  for (int t = 0; t < NTYPES; ++t) mx[t] = decf(mb[t]);
  double s[NTYPES];
  #pragma unroll
  for (int t = 0; t < NTYPES; ++t) s[t] = 0.0;
  for (int r = blockIdx.x * 256 + threadIdx.x; r < nrows; r += gridDim.x * 256) {
    #pragma unroll
    for (int t = 0; t < NTYPES; ++t)
      s[t] += exp((double)L[(size_t)r * NTYPES + t] - (double)mx[t]);
  }
  #pragma unroll
  for (int t = 0; t < NTYPES; ++t) sm[threadIdx.x][t] = s[t];
  __syncthreads();
  for (int st = 128; st > 0; st >>= 1) {
    if (threadIdx.x < st)
      for (int t = 0; t < NTYPES; ++t)
        sm[threadIdx.x][t] += sm[threadIdx.x + st][t];
    __syncthreads();
  }
  if (threadIdx.x < NTYPES) atomicAdd(&sums[threadIdx.x], sm[0][threadIdx.x]);
}

// ---------------- fused probs + gumbel sampling (start head) ----------------
__global__ __launch_bounds__(256) void k_ps_start(const float* __restrict__ L,
                                                  const uint32_t* __restrict__ mb,
                                                  const double* __restrict__ sums,
                                                  float* __restrict__ P,
                                                  float* __restrict__ outSN,
                                                  int* __restrict__ sn,
                                                  int* __restrict__ flags) {
  int i = blockIdx.x * 256 + threadIdx.x;
  if (i >= NT) return;
  uint32_t a0, a1, b0, b1; derive_keys(a0, a1, b0, b1);
  double best = -1e300; int bi = 0;
  #pragma unroll
  for (int t = 0; t < NTYPES; ++t) {
    double p = exp((double)L[(size_t)i * NTYPES + t] - (double)decf(mb[t])) / sums[t];
    float pf = (float)p;
    if (i >= N_GRAPH || pf == 0.0f) pf = 1e-10f;
    P[(size_t)i * NTYPES + t] = pf;
    uint32_t bits = rng_bits(a0, a1, (uint32_t)(i * NTYPES + t), (uint32_t)(NT * NTYPES));
    double v = log((double)pf) + gumbel_from_bits(bits);
    if (v > best) { best = v; bi = t; }
  }
  sn[i] = bi;
  outSN[i] = (float)bi;
  flags[bi] = 1;   // benign race: all writers store 1
}

// ---------------- fused probs + gumbel sampling (end head) ----------------
__global__ __launch_bounds__(256) void k_ps_end(const float* __restrict__ L,
                                                const uint32_t* __restrict__ mb,
                                                const double* __restrict__ sums,
                                                const int* __restrict__ flags,
                                                float* __restrict__ P,
                                                float* __restrict__ outEN) {
  int j = blockIdx.x * 256 + threadIdx.x;
  if (j >= 2 * NT) return;
  uint32_t a0, a1, b0, b1; derive_keys(a0, a1, b0, b1);
  const bool rowmask = (j < NTYPES && flags[j]);
  double best = -1e300; int bi = 0;
  #pragma unroll
  for (int t = 0; t < NTYPES; ++t) {
    double p = exp((double)L[(size_t)j * NTYPES + t] - (double)decf(mb[t])) / sums[t];
    float pf = (float)p;
    if (rowmask || pf == 0.0f) pf = 1e-10f;
    P[(size_t)j * NTYPES + t] = pf;
    uint32_t bits = rng_bits(b0, b1, (uint32_t)(j * NTYPES + t), (uint32_t)(2 * NT * NTYPES));
    double v = log((double)pf) + gumbel_from_bits(bits);
    if (v > best) { best = v; bi = t; }
  }
  outEN[j] = (float)bi;
}

// ---------------- host ----------------
extern "C" void kernel_launch(void* const* d_in, const int* in_sizes, int n_in,
                              void* d_out, int out_size, void* d_ws, size_t ws_size,
                              hipStream_t stream) {
  const float* x    = (const float*)d_in[0];
  const float* cand = (const float*)d_in[1];
  const int*   ei   = (const int*)d_in[2];
  const float* W1 = (const float*)d_in[4];  const float* b1 = (const float*)d_in[5];
  const float* W2 = (const float*)d_in[6];  const float* b2 = (const float*)d_in[7];
  const float* W3 = (const float*)d_in[8];  const float* b3 = (const float*)d_in[9];
  const float* Ws1 = (const float*)d_in[10]; const float* bs1 = (const float*)d_in[11];
  const float* Ws2 = (const float*)d_in[12]; const float* bs2 = (const float*)d_in[13];
  const float* We1 = (const float*)d_in[14]; const float* be1 = (const float*)d_in[15];
  const float* We2 = (const float*)d_in[16]; const float* be2 = (const float*)d_in[17];
  float* out = (float*)d_out;
  float* outSN = out;
  float* outEN = out + NT;
  float* outPS = out + 3 * NT;
  float* outPE = out + 13 * NT;

  char* ws = (char*)d_ws;
  size_t off = 0;
  auto alloc = [&](size_t bytes) -> void* {
    void* p = ws + off;
    off += (bytes + 511) & ~(size_t)511;
    return p;
  };
  float*    dinv    = (float*)alloc((size_t)NT * 4);
  int*      rowptr  = (int*)alloc((size_t)(NT + 1) * 4);
  int*      cnt     = (int*)alloc((size_t)NBK2 * 4);
  int*      rowbase = (int*)alloc((size_t)NBK2 * 4);
  int*      cmat    = (int*)alloc((size_t)(NMAT + 1) * 4);
  int*      partial = (int*)alloc(512 * 4);
  int*      col     = (int*)alloc((size_t)NE * 4);
  // tmpent (~31.6 MB) aliases zsA + zsB + Ha (all dead until after k_place)
  char*     ublk    = (char*)alloc((size_t)TMPENT_CAP * 4);
  uint32_t* tmpent  = (uint32_t*)ublk;
  float*    zsA     = (float*)ublk;                                    // [NT][16] = 6.4 MB
  float*    zsB     = (float*)(ublk + (size_t)NT * 16 * 4);            // [NT][16] = 6.4 MB
  float*    Ha      = (float*)(ublk + (size_t)NT * 16 * 4 * 2);        // 12.8 MB
  float*    logitsS = (float*)alloc((size_t)NT * NTYPES * 4);
  float*    logitsE = (float*)alloc((size_t)2 * NT * NTYPES * 4);
  float*    w1v     = (float*)alloc((size_t)NT * 4);
  float*    ws1v    = (float*)alloc((size_t)NT * 4);
  float*    w2v     = (float*)alloc((size_t)NT * 4);
  float*    wsd     = (float*)alloc((size_t)NT * 4);   // dummy scaled-out of prop2
  double*   Md      = (double*)alloc(512 * 8);
  double*   ud      = (double*)alloc(32 * 8);
  double*   vd      = (double*)alloc(32 * 8);
  int*      sn      = (int*)alloc((size_t)NT * 4);
  uint32_t* maxS    = (uint32_t*)alloc(64);
  double*   sumS    = (double*)alloc(128);
  uint32_t* maxE    = (uint32_t*)alloc(64);
  double*   sumE    = (double*)alloc(128);
  int*      flags   = (int*)alloc(64);
  (void)ws_size; (void)in_sizes; (void)n_in; (void)out_size;

  const int* srcA = ei;
  const int* dstA = ei + NE;

  const int B = 256;
  auto blocks = [](long long nthreads) { return (int)((nthreads + 255) / 256); };

  // CSR build: count -> scan (+rowscan merged into s2) -> barrier-free scatter -> place
  hipMemsetAsync(cnt, 0, (size_t)NBK2 * 4, stream);
  k_bcount<<<SB, 512, 0, stream>>>(dstA, cmat, cnt);
  k_s1<<<NSCAN_B, 256, 0, stream>>>(cmat, partial);
  k_s2<<<1, 512, 0, stream>>>(partial, cmat, cnt, rowbase);
  k_s3<<<NSCAN_B, 256, 0, stream>>>(cmat, partial);
  k_scatter2<<<SB, 512, 0, stream>>>(srcA, dstA, cmat, tmpent);
  k_place<<<NBK2, 512, 0, stream>>>(tmpent, cmat, rowbase, rowptr, dinv, col);

  // linear GCN stack folded to three 16-feature propagations (1 cacheline/edge)
  // + scalar w-props + dense epilogue
  k_small<<<1, 512, 0, stream>>>(W2, b2, W3, b1, Md, ud, vd);
  k_mm1<<<blocks((long long)NT * 4), B, 0, stream>>>(x, cand, W1, dinv, zsA);
  const int PR3 = 32, PBLK = (NT + PR3 - 1) / PR3;    // 3126 blocks, 8x32 = 256 thr
  k_prop3<true,  true,  PR3><<<PBLK, dim3(8, PR3), 0, stream>>>(rowptr, col, zsA, dinv, dinv, zsB, w1v, ws1v);
  k_prop3<true,  true,  PR3><<<PBLK, dim3(8, PR3), 0, stream>>>(rowptr, col, zsB, ws1v, dinv, zsA, w2v, wsd);
  k_prop3<false, false, PR3><<<PBLK, dim3(8, PR3), 0, stream>>>(rowptr, col, zsA, nullptr, dinv, zsB, nullptr, nullptr);
  k_epi<<<blocks((long long)NT * 32), B, 0, stream>>>(zsB, w1v, w2v, Md, ud, vd, b3, Ha);
  // H3 = Ha

  // start head
  k_head<16><<<blocks(NT), B, 0, stream>>>(Ha, sn, NT, Ws1, bs1, Ws2, bs2, logitsS);
  hipMemsetAsync(maxS, 0, (size_t)((char*)flags - (char*)maxS) + 512, stream);
  k_colmax<<<512, B, 0, stream>>>(logitsS, NT, maxS);
  k_colsum<<<512, B, 0, stream>>>(logitsS, NT, maxS, sumS);
  k_ps_start<<<blocks(NT), B, 0, stream>>>(logitsS, maxS, sumS, outPS, outSN, sn, flags);

  // end head (rows: [H3; H3[sn]])
  k_head<24><<<blocks(2 * NT), B, 0, stream>>>(Ha, sn, 2 * NT, We1, be1, We2, be2, logitsE);
  k_colmax<<<512, B, 0, stream>>>(logitsE, 2 * NT, maxE);
  k_colsum<<<512, B, 0, stream>>>(logitsE, 2 * NT, maxE, sumE);
  k_ps_end<<<blocks((long long)2 * NT), B, 0, stream>>>(logitsE, maxE, sumE, flags, outPE, outEN);
}